// Round 6
// baseline (231.762 us; speedup 1.0000x reference)
//
#include <hip/hip_runtime.h>
#include <hip/hip_bf16.h>

#define B_DIM 128
#define S_DIM 64
#define DIN   2048
#define DOUT  2048
#define NLAYERS 64

#define BM 128
#define BN 64
#define BK 64
#define NK (DIN / BK)
#define TPP (DOUT / BN)                 // tiles per position = 32
#define NTILES (S_DIM * TPP)            // 2048
#define NXCD 8
// A-buffer pad: folds the occupancy-limiting pad into the dbuf arrays so it
// can't be DCE'd. Total LDS = 2*(16K+4K) + 2*8K = 56KB -> exactly 2 blocks/CU
// (keeps the active-position window at 2/XCD -> L2-fitting working set).
#define APADE 2048                      // bf16 elements of pad per A buffer

typedef __bf16 bf16_t;
typedef __attribute__((ext_vector_type(8))) bf16_t bf16x8;
typedef __attribute__((ext_vector_type(4))) float f32x4;

// Parallel rank sort: perm = positions ordered by (layer, s).
__global__ void rank_sort(const int* __restrict__ layer_idx, int* __restrict__ perm) {
    __shared__ int L[S_DIM];
    const int s = threadIdx.x;
    L[s] = layer_idx[s];
    __syncthreads();
    const int mine = L[s];
    int rank = 0;
    #pragma unroll
    for (int t = 0; t < S_DIM; ++t) {
        const int lt = L[t];
        rank += (lt < mine || (lt == mine && t < s)) ? 1 : 0;
    }
    perm[rank] = s;
}

// Streaming pre-pass: x fp32 -> bf16 (halves x bytes and L2 working set).
__global__ void convert_x(const float* __restrict__ x, bf16_t* __restrict__ x16) {
    const size_t i = ((size_t)blockIdx.x * 256 + threadIdx.x) * 8;
    f32x4 a = *(const f32x4*)(x + i);
    f32x4 b = *(const f32x4*)(x + i + 4);
    bf16x8 v;
    #pragma unroll
    for (int j = 0; j < 4; ++j) { v[j] = (bf16_t)a[j]; v[j + 4] = (bf16_t)b[j]; }
    *(bf16x8*)(x16 + i) = v;
}

// 128x64 tile/block; LDS double-buffer, ONE barrier per K-step, 2-deep issue:
// loads for tile k+2 issue as soon as tile k+1's registers retire to LDS, so
// they are in flight for a full K-step (covers HBM latency).
template <bool XBF16>
__launch_bounds__(256, 2)
__global__ void flex_linear_gemm(const float* __restrict__ x,
                                 const bf16_t* __restrict__ x16,
                                 const float* __restrict__ w,
                                 const int* __restrict__ layer_idx,
                                 const int* __restrict__ perm,
                                 float* __restrict__ out) {
    __shared__ bf16_t Alds[2][BM * BK + APADE];  // XOR-swizzled [128][64] x2
    __shared__ bf16_t Blds[2][BN * BK];          // XOR-swizzled [64][64]  x2

    // ---- XCD-chunked swizzle (2048 % 8 == 0 -> bijective) ----
    const int orig = blockIdx.x;
    const int xcd  = orig & (NXCD - 1);
    const int slot = orig >> 3;                  // 0..255 within XCD
    const int tile = xcd * (NTILES / NXCD) + slot;
    const int yy   = tile / TPP;                 // sorted-position rank
    const int nb   = tile % TPP;                 // output column block (0..31)

    const int s  = perm[yy];
    const int layer = layer_idx[s];

    const float* Bg = w + (size_t)layer * (size_t)(DOUT * DIN) + (size_t)(nb * BN) * DIN;

    const int tid  = threadIdx.x;
    const int lane = tid & 63;
    const int wave = tid >> 6;
    const int wr = (wave >> 1) * 64;    // M offset (0/64)
    const int wc = (wave & 1) * 32;     // N offset (0/32)
    const int lrow = lane & 15;
    const int lk   = (lane >> 4) * 8;

    // ---- hoisted addresses ----
    int offWA[4], offWB[2];
    const float*  pA[4];
    const bf16_t* pA16[4];
    const float*  pB[2];
    #pragma unroll
    for (int i = 0; i < 4; ++i) {
        const int c   = tid + 256 * i;
        const int row = c >> 3;              // 0..127 (b index)
        const int kc8 = (c & 7) * 8;
        offWA[i] = (row * BK + kc8) ^ ((row & 7) << 3);
        const size_t aoff = (size_t)row * (S_DIM * DIN) + (size_t)s * DIN + kc8;
        pA[i]   = x   + aoff;
        pA16[i] = x16 + aoff;
    }
    #pragma unroll
    for (int i = 0; i < 2; ++i) {
        const int c   = tid + 256 * i;
        const int row = c >> 3;              // 0..63 (o index within tile)
        const int kc8 = (c & 7) * 8;
        offWB[i] = (row * BK + kc8) ^ ((row & 7) << 3);
        pB[i] = Bg + (size_t)row * DIN + kc8;
    }
    int offA[2][4], offB[2][2];
    #pragma unroll
    for (int kk = 0; kk < 2; ++kk) {
        #pragma unroll
        for (int m = 0; m < 4; ++m) {
            const int ra = wr + m * 16 + lrow;
            offA[kk][m] = (ra * BK + kk * 32 + lk) ^ ((ra & 7) << 3);
        }
        #pragma unroll
        for (int n = 0; n < 2; ++n) {
            const int rb = wc + n * 16 + lrow;
            offB[kk][n] = (rb * BK + kk * 32 + lk) ^ ((rb & 7) << 3);
        }
    }

    bf16x8 RA16[4];           // in-flight A (bf16 path)
    f32x4  RA[8];             // in-flight A (fp32 fallback)
    f32x4  RB[4];             // in-flight B fp32
    f32x4  acc[4][2] = {};

    auto issue = [&](int kb) {
        const int koff = kb * BK;
        #pragma unroll
        for (int i = 0; i < 4; ++i) {
            if constexpr (XBF16) {
                RA16[i] = *(const bf16x8*)(pA16[i] + koff);
            } else {
                const float* a = pA[i] + koff;
                RA[2 * i]     = *(const f32x4*)a;
                RA[2 * i + 1] = *(const f32x4*)(a + 4);
            }
        }
        #pragma unroll
        for (int i = 0; i < 2; ++i) {
            const float* b = pB[i] + koff;
            RB[2 * i]     = *(const f32x4*)b;
            RB[2 * i + 1] = *(const f32x4*)(b + 4);
        }
    };
    auto cvt_write = [&](int buf) {
        bf16_t* Al = &Alds[buf][0];
        bf16_t* Bl = &Blds[buf][0];
        #pragma unroll
        for (int i = 0; i < 4; ++i) {
            if constexpr (XBF16) {
                *(bf16x8*)&Al[offWA[i]] = RA16[i];
            } else {
                bf16x8 va;
                #pragma unroll
                for (int j = 0; j < 4; ++j) {
                    va[j]     = (bf16_t)RA[2 * i][j];
                    va[j + 4] = (bf16_t)RA[2 * i + 1][j];
                }
                *(bf16x8*)&Al[offWA[i]] = va;
            }
        }
        #pragma unroll
        for (int i = 0; i < 2; ++i) {
            bf16x8 vb;
            #pragma unroll
            for (int j = 0; j < 4; ++j) {
                vb[j]     = (bf16_t)RB[2 * i][j];
                vb[j + 4] = (bf16_t)RB[2 * i + 1][j];
            }
            *(bf16x8*)&Bl[offWB[i]] = vb;
        }
    };
    auto compute = [&](int buf) {
        const bf16_t* Al = &Alds[buf][0];
        const bf16_t* Bl = &Blds[buf][0];
        #pragma unroll
        for (int kk = 0; kk < 2; ++kk) {
            bf16x8 af[4], bfr[2];
            #pragma unroll
            for (int m = 0; m < 4; ++m) af[m]  = *(const bf16x8*)&Al[offA[kk][m]];
            #pragma unroll
            for (int n = 0; n < 2; ++n) bfr[n] = *(const bf16x8*)&Bl[offB[kk][n]];
            #pragma unroll
            for (int m = 0; m < 4; ++m)
                #pragma unroll
                for (int n = 0; n < 2; ++n)
                    acc[m][n] = __builtin_amdgcn_mfma_f32_16x16x32_bf16(af[m], bfr[n], acc[m][n], 0, 0, 0);
        }
    };

    // ---- dbuf pipeline: ONE barrier per K-step, 2-deep issue distance ----
    issue(0);
    cvt_write(0);                    // waits on k=0 loads (once)
    issue(1);                        // k=1 loads in flight across iter 0
    for (int kb = 0; kb < NK - 1; ++kb) {
        __syncthreads();             // buf[kb&1] visible; buf[(kb+1)&1] free
        compute(kb & 1);
        cvt_write((kb + 1) & 1);     // k+1 loads have had a full K-step
        if (kb + 2 < NK) issue(kb + 2);
    }
    __syncthreads();
    compute((NK - 1) & 1);

    // ---- epilogue (nt stores: out never re-read; keep L2 for x/w) ----
    float* Og = out + (size_t)s * DOUT + (size_t)(nb * BN);
    #pragma unroll
    for (int m = 0; m < 4; ++m) {
        const int rb = wr + m * 16 + (lane >> 4) * 4;
        #pragma unroll
        for (int r = 0; r < 4; ++r) {
            float* orow = Og + (size_t)(rb + r) * (S_DIM * DOUT);
            #pragma unroll
            for (int n = 0; n < 2; ++n)
                __builtin_nontemporal_store(acc[m][n][r], &orow[wc + n * 16 + (lane & 15)]);
        }
    }
}

extern "C" void kernel_launch(void* const* d_in, const int* in_sizes, int n_in,
                              void* d_out, int out_size, void* d_ws, size_t ws_size,
                              hipStream_t stream) {
    const float* x         = (const float*)d_in[0];
    const float* w         = (const float*)d_in[1];
    const int*   layer_idx = (const int*)d_in[2];
    float*       out       = (float*)d_out;

    int*    perm = (int*)d_ws;
    bf16_t* x16  = (bf16_t*)((char*)d_ws + 512);
    const size_t need = 512 + (size_t)B_DIM * S_DIM * DIN * sizeof(bf16_t);

    rank_sort<<<1, S_DIM, 0, stream>>>(layer_idx, perm);

    if (ws_size >= need) {
        convert_x<<<(B_DIM * S_DIM * DIN / 8) / 256, 256, 0, stream>>>(x, x16);
        flex_linear_gemm<true><<<NTILES, dim3(256), 0, stream>>>(x, x16, w, layer_idx, perm, out);
    } else {
        flex_linear_gemm<false><<<NTILES, dim3(256), 0, stream>>>(x, x16, w, layer_idx, perm, out);
    }
}

// Round 7
// 223.992 us; speedup vs baseline: 1.0347x; 1.0347x over previous
//
#include <hip/hip_runtime.h>
#include <hip/hip_bf16.h>

#define B_DIM 128
#define S_DIM 64
#define DIN   2048
#define DOUT  2048
#define NLAYERS 64

#define BM 128
#define BN 64
#define BK 64
#define NK (DIN / BK)
#define TPP (DOUT / BN)                 // tiles per position = 32
#define NTILES (S_DIM * TPP)            // 2048
#define NXCD 8
// LDS pad so exactly 2 blocks/CU fit: keeps the concurrent working set per
// XCD at ~2 positions' x + one layer K-slice (< 4MB L2).
#define APAD 16384                      // bf16 elements of pad

typedef __bf16 bf16_t;
typedef __attribute__((ext_vector_type(8))) bf16_t bf16x8;
typedef __attribute__((ext_vector_type(4))) float f32x4;

// Rank sort + LOCKSTEP tile schedule. For each layer-group of c sorted
// positions, tiles are ordered nb-major: slot = gstart*32 + nb*c + gpos.
// Same-layer positions' identical-weight tiles are then ADJACENT in dispatch
// order -> concurrent on the same XCD at the same K-phase -> L2 dedups the
// duplicate weight fetches.
__global__ void rank_sort(const int* __restrict__ layer_idx, int* __restrict__ tilemap) {
    __shared__ int L[S_DIM];
    const int s = threadIdx.x;
    L[s] = layer_idx[s];
    __syncthreads();
    const int mine = L[s];
    int rank = 0, gstart = 0, gcount = 0;
    #pragma unroll
    for (int t = 0; t < S_DIM; ++t) {
        const int lt = L[t];
        rank   += (lt < mine || (lt == mine && t < s)) ? 1 : 0;
        gstart += (lt <  mine) ? 1 : 0;
        gcount += (lt == mine) ? 1 : 0;
    }
    const int gpos = rank - gstart;
    for (int nb = 0; nb < TPP; ++nb)
        tilemap[gstart * TPP + nb * gcount + gpos] = (s << 5) | nb;
}

// Streaming pre-pass: x fp32 -> bf16 (halves x bytes and L2 working set).
__global__ void convert_x(const float* __restrict__ x, bf16_t* __restrict__ x16) {
    const size_t i = ((size_t)blockIdx.x * 256 + threadIdx.x) * 8;
    f32x4 a = *(const f32x4*)(x + i);
    f32x4 b = *(const f32x4*)(x + i + 4);
    bf16x8 v;
    #pragma unroll
    for (int j = 0; j < 4; ++j) { v[j] = (bf16_t)a[j]; v[j + 4] = (bf16_t)b[j]; }
    *(bf16x8*)(x16 + i) = v;
}

// 128x64 tile/block, T14 issue-early pipeline (round-5 structure: single LDS
// buffer, 2 barriers/K-step -- measured equal to dbuf, smaller LDS), cached
// weight loads (L2 dedup), nt epilogue stores, XCD-chunked lockstep schedule.
template <bool XBF16>
__launch_bounds__(256, 2)
__global__ void flex_linear_gemm(const float* __restrict__ x,
                                 const bf16_t* __restrict__ x16,
                                 const float* __restrict__ w,
                                 const int* __restrict__ layer_idx,
                                 const int* __restrict__ tilemap,
                                 float* __restrict__ out) {
    __shared__ bf16_t Alds[BM * BK + APAD];  // XOR-swizzled [128][64] + pad
    __shared__ bf16_t Blds[BN * BK];         // XOR-swizzled [64][64]

    // ---- XCD-chunked slot -> lockstep tile ----
    const int orig = blockIdx.x;
    const int xcd  = orig & (NXCD - 1);
    const int slot = orig >> 3;                  // 0..255 within XCD
    const int val  = tilemap[xcd * (NTILES / NXCD) + slot];
    const int s    = val >> 5;
    const int nb   = val & 31;
    const int layer = layer_idx[s];

    const float* Bg = w + (size_t)layer * (size_t)(DOUT * DIN) + (size_t)(nb * BN) * DIN;

    const int tid  = threadIdx.x;
    const int lane = tid & 63;
    const int wave = tid >> 6;
    const int wr = (wave >> 1) * 64;    // M offset (0/64)
    const int wc = (wave & 1) * 32;     // N offset (0/32)
    const int lrow = lane & 15;
    const int lk   = (lane >> 4) * 8;

    // ---- hoisted addresses ----
    int offWA[4], offWB[2];
    const float*  pA[4];
    const bf16_t* pA16[4];
    const float*  pB[2];
    #pragma unroll
    for (int i = 0; i < 4; ++i) {
        const int c   = tid + 256 * i;
        const int row = c >> 3;              // 0..127 (b index)
        const int kc8 = (c & 7) * 8;
        offWA[i] = (row * BK + kc8) ^ ((row & 7) << 3);
        const size_t aoff = (size_t)row * (S_DIM * DIN) + (size_t)s * DIN + kc8;
        pA[i]   = x   + aoff;
        pA16[i] = x16 + aoff;
    }
    #pragma unroll
    for (int i = 0; i < 2; ++i) {
        const int c   = tid + 256 * i;
        const int row = c >> 3;              // 0..63 (o index within tile)
        const int kc8 = (c & 7) * 8;
        offWB[i] = (row * BK + kc8) ^ ((row & 7) << 3);
        pB[i] = Bg + (size_t)row * DIN + kc8;
    }
    int offA[2][4], offB[2][2];
    #pragma unroll
    for (int kk = 0; kk < 2; ++kk) {
        #pragma unroll
        for (int m = 0; m < 4; ++m) {
            const int ra = wr + m * 16 + lrow;
            offA[kk][m] = (ra * BK + kk * 32 + lk) ^ ((ra & 7) << 3);
        }
        #pragma unroll
        for (int n = 0; n < 2; ++n) {
            const int rb = wc + n * 16 + lrow;
            offB[kk][n] = (rb * BK + kk * 32 + lk) ^ ((rb & 7) << 3);
        }
    }

    bf16x8 RA16[4];           // in-flight A (bf16 path)
    f32x4  RA[8];             // in-flight A (fp32 fallback)
    f32x4  RB[4];             // in-flight B fp32
    f32x4  acc[4][2] = {};

    auto issue = [&](int kb) {
        const int koff = kb * BK;
        #pragma unroll
        for (int i = 0; i < 4; ++i) {
            if constexpr (XBF16) {
                RA16[i] = *(const bf16x8*)(pA16[i] + koff);
            } else {
                const float* a = pA[i] + koff;
                RA[2 * i]     = *(const f32x4*)a;
                RA[2 * i + 1] = *(const f32x4*)(a + 4);
            }
        }
        #pragma unroll
        for (int i = 0; i < 2; ++i) {
            const float* b = pB[i] + koff;
            RB[2 * i]     = *(const f32x4*)b;
            RB[2 * i + 1] = *(const f32x4*)(b + 4);
        }
    };
    auto cvt_write = [&]() {
        #pragma unroll
        for (int i = 0; i < 4; ++i) {
            if constexpr (XBF16) {
                *(bf16x8*)&Alds[offWA[i]] = RA16[i];
            } else {
                bf16x8 va;
                #pragma unroll
                for (int j = 0; j < 4; ++j) {
                    va[j]     = (bf16_t)RA[2 * i][j];
                    va[j + 4] = (bf16_t)RA[2 * i + 1][j];
                }
                *(bf16x8*)&Alds[offWA[i]] = va;
            }
        }
        #pragma unroll
        for (int i = 0; i < 2; ++i) {
            bf16x8 vb;
            #pragma unroll
            for (int j = 0; j < 4; ++j) {
                vb[j]     = (bf16_t)RB[2 * i][j];
                vb[j + 4] = (bf16_t)RB[2 * i + 1][j];
            }
            *(bf16x8*)&Blds[offWB[i]] = vb;
        }
    };
    auto compute = [&]() {
        #pragma unroll
        for (int kk = 0; kk < 2; ++kk) {
            bf16x8 af[4], bfr[2];
            #pragma unroll
            for (int m = 0; m < 4; ++m) af[m]  = *(const bf16x8*)&Alds[offA[kk][m]];
            #pragma unroll
            for (int n = 0; n < 2; ++n) bfr[n] = *(const bf16x8*)&Blds[offB[kk][n]];
            #pragma unroll
            for (int m = 0; m < 4; ++m)
                #pragma unroll
                for (int n = 0; n < 2; ++n)
                    acc[m][n] = __builtin_amdgcn_mfma_f32_16x16x32_bf16(af[m], bfr[n], acc[m][n], 0, 0, 0);
        }
    };

    // ---- pipelined main loop: 2 barriers per K-step ----
    issue(0);
    cvt_write();
    for (int kb = 0; kb < NK - 1; ++kb) {
        __syncthreads();
        issue(kb + 1);
        compute();
        __syncthreads();
        cvt_write();
    }
    __syncthreads();
    compute();

    // ---- epilogue (nt stores: out never re-read; keep L2 for x/w) ----
    float* Og = out + (size_t)s * DOUT + (size_t)(nb * BN);
    #pragma unroll
    for (int m = 0; m < 4; ++m) {
        const int rb = wr + m * 16 + (lane >> 4) * 4;
        #pragma unroll
        for (int r = 0; r < 4; ++r) {
            float* orow = Og + (size_t)(rb + r) * (S_DIM * DOUT);
            #pragma unroll
            for (int n = 0; n < 2; ++n)
                __builtin_nontemporal_store(acc[m][n][r], &orow[wc + n * 16 + (lane & 15)]);
        }
    }
}

extern "C" void kernel_launch(void* const* d_in, const int* in_sizes, int n_in,
                              void* d_out, int out_size, void* d_ws, size_t ws_size,
                              hipStream_t stream) {
    const float* x         = (const float*)d_in[0];
    const float* w         = (const float*)d_in[1];
    const int*   layer_idx = (const int*)d_in[2];
    float*       out       = (float*)d_out;

    int*    tilemap = (int*)d_ws;                      // 2048 ints = 8 KB
    bf16_t* x16     = (bf16_t*)((char*)d_ws + 16384);  // 32 MB
    const size_t need = 16384 + (size_t)B_DIM * S_DIM * DIN * sizeof(bf16_t);

    rank_sort<<<1, S_DIM, 0, stream>>>(layer_idx, tilemap);

    if (ws_size >= need) {
        convert_x<<<(B_DIM * S_DIM * DIN / 8) / 256, 256, 0, stream>>>(x, x16);
        flex_linear_gemm<true><<<NTILES, dim3(256), 0, stream>>>(x, x16, w, layer_idx, tilemap, out);
    } else {
        flex_linear_gemm<false><<<NTILES, dim3(256), 0, stream>>>(x, x16, w, layer_idx, tilemap, out);
    }
}

// Round 8
// 222.887 us; speedup vs baseline: 1.0398x; 1.0050x over previous
//
#include <hip/hip_runtime.h>
#include <hip/hip_bf16.h>

#define B_DIM 128
#define S_DIM 64
#define DIN   2048
#define DOUT  2048
#define NLAYERS 64

#define BM 128
#define BN 64
#define BK 64
#define NK (DIN / BK)
#define TPP (DOUT / BN)                 // tiles per position = 32
#define NTILES (S_DIM * TPP)            // 2048 slots (fixed grid)
#define NXCD 8

// LDS layout (bf16 elems): A0 [0,8192) A1 [8192,16384) B [16384,20480)
// + pad tail so total = 56KB -> exactly 2 blocks/CU (keeps per-XCD working
// set at ~2 chunks -> x + weight K-slices fit in 4MB L2).
#define A0_OFF 0
#define A1_OFF (BM * BK)
#define B_OFF  (2 * BM * BK)
#define LDS_ELEMS (2 * BM * BK + BN * BK + 8192)   // 28672 elems = 56 KB

typedef __bf16 bf16_t;
typedef __attribute__((ext_vector_type(8))) bf16_t bf16x8;
typedef __attribute__((ext_vector_type(4))) float f32x4;

// Build the merged-chunk schedule. Positions sorted by (layer, s); each
// layer-group is split into chunks of <=2 positions. A chunk's 32 nb-tiles
// share ONE weight fetch (structural dedup -- no cache dependence).
// XCD assignment balances by POSITION count: chunk -> xcd = cumPositions>>3,
// so every XCD gets exactly 8 positions' worth of work; max 8 chunks = 256
// slots per XCD region. Unused slots = -1.
__global__ void rank_sort(const int* __restrict__ layer_idx, int* __restrict__ tilemap) {
    __shared__ int L[S_DIM], gposA[S_DIM];
    __shared__ int chunkWork[S_DIM];
    const int s = threadIdx.x;
    L[s] = layer_idx[s];
    __syncthreads();
    const int mine = L[s];
    int rank = 0, gstart = 0;
    for (int t = 0; t < S_DIM; ++t) {
        const int lt = L[t];
        rank   += (lt < mine || (lt == mine && t < s)) ? 1 : 0;
        gstart += (lt <  mine) ? 1 : 0;
    }
    const int gpos = rank - gstart;
    gposA[s] = gpos;
    __syncthreads();
    const bool prim = (gpos & 1) == 0;
    // chunk index = #primaries strictly before me in (layer, gpos) order
    int cidx = 0, partner = -1;
    for (int t = 0; t < S_DIM; ++t) {
        if (((gposA[t] & 1) == 0) && (L[t] < mine || (L[t] == mine && gposA[t] < gpos))) cidx++;
        if (L[t] == mine && gposA[t] == gpos + 1) partner = t;
    }
    if (prim) chunkWork[cidx] = (partner >= 0) ? 2 : 1;
    // init tilemap
    for (int i = 0; i < NTILES / S_DIM; ++i) tilemap[s * (NTILES / S_DIM) + i] = -1;
    __syncthreads();
    if (prim) {
        int cum = 0;
        for (int j = 0; j < cidx; ++j) cum += chunkWork[j];
        const int xcd = cum >> 3;              // 8 positions of work per XCD
        int off = 0, c2 = 0;
        for (int j = 0; j < cidx; ++j) { if ((c2 >> 3) == xcd) off++; c2 += chunkWork[j]; }
        const int base = xcd * (NTILES / NXCD) + off * TPP;
        const int code = (s << 5) | ((partner + 1) << 11);
        for (int nb = 0; nb < TPP; ++nb) tilemap[base + nb] = code | nb;
    }
}

// Streaming pre-pass: x fp32 -> bf16 (halves x bytes and L2 working set).
__global__ void convert_x(const float* __restrict__ x, bf16_t* __restrict__ x16) {
    const size_t i = ((size_t)blockIdx.x * 256 + threadIdx.x) * 8;
    f32x4 a = *(const f32x4*)(x + i);
    f32x4 b = *(const f32x4*)(x + i + 4);
    bf16x8 v;
    #pragma unroll
    for (int j = 0; j < 4; ++j) { v[j] = (bf16_t)a[j]; v[j + 4] = (bf16_t)b[j]; }
    *(bf16x8*)(x16 + i) = v;
}

// Merged-pair GEMM: one block = (chunk, nb). Weight tile staged ONCE in LDS,
// multiplied against up to 2 positions' A tiles. T14 issue-early pipeline,
// 2 barriers/K-step, nt epilogue stores.
template <bool XBF16>
__launch_bounds__(256, 2)
__global__ void flex_linear_gemm(const float* __restrict__ x,
                                 const bf16_t* __restrict__ x16,
                                 const float* __restrict__ w,
                                 const int* __restrict__ layer_idx,
                                 const int* __restrict__ tilemap,
                                 float* __restrict__ out) {
    __shared__ bf16_t lds[LDS_ELEMS];

    const int e = tilemap[blockIdx.x];
    if (e < 0) return;
    const int nb   = e & 31;
    const int s0   = (e >> 5) & 63;
    const int s1p1 = (e >> 11) & 127;
    const bool has2 = s1p1 > 0;
    const int s1   = has2 ? (s1p1 - 1) : s0;
    const int layer = layer_idx[s0];

    const float* Bg = w + (size_t)layer * (size_t)(DOUT * DIN) + (size_t)(nb * BN) * DIN;

    const int tid  = threadIdx.x;
    const int lane = tid & 63;
    const int wave = tid >> 6;
    const int wr = (wave >> 1) * 64;    // M offset (0/64)
    const int wc = (wave & 1) * 32;     // N offset (0/32)
    const int lrow = lane & 15;
    const int lk   = (lane >> 4) * 8;

    // ---- hoisted addresses ----
    int offWA[4], offWB[2];
    const float*  pA0[4], *pA1[4];
    const bf16_t* pA016[4], *pA116[4];
    const float*  pB[2];
    #pragma unroll
    for (int i = 0; i < 4; ++i) {
        const int c   = tid + 256 * i;
        const int row = c >> 3;              // 0..127 (b index)
        const int kc8 = (c & 7) * 8;
        offWA[i] = (row * BK + kc8) ^ ((row & 7) << 3);
        const size_t base = (size_t)row * (S_DIM * DIN) + kc8;
        pA0[i]   = x   + base + (size_t)s0 * DIN;
        pA016[i] = x16 + base + (size_t)s0 * DIN;
        pA1[i]   = x   + base + (size_t)s1 * DIN;
        pA116[i] = x16 + base + (size_t)s1 * DIN;
    }
    #pragma unroll
    for (int i = 0; i < 2; ++i) {
        const int c   = tid + 256 * i;
        const int row = c >> 3;              // 0..63 (o index within tile)
        const int kc8 = (c & 7) * 8;
        offWB[i] = (row * BK + kc8) ^ ((row & 7) << 3);
        pB[i] = Bg + (size_t)row * DIN + kc8;
    }
    int offA[2][4], offB[2][2];
    #pragma unroll
    for (int kk = 0; kk < 2; ++kk) {
        #pragma unroll
        for (int m = 0; m < 4; ++m) {
            const int ra = wr + m * 16 + lrow;
            offA[kk][m] = (ra * BK + kk * 32 + lk) ^ ((ra & 7) << 3);
        }
        #pragma unroll
        for (int n = 0; n < 2; ++n) {
            const int rb = wc + n * 16 + lrow;
            offB[kk][n] = (rb * BK + kk * 32 + lk) ^ ((rb & 7) << 3);
        }
    }

    bf16x8 RA0[4], RA1[4];    // in-flight A (bf16 path)
    f32x4  RAF0[8], RAF1[8];  // in-flight A (fp32 fallback)
    f32x4  RB[4];             // in-flight B fp32
    f32x4  acc0[4][2] = {}, acc1[4][2] = {};

    auto issue = [&](int kb) {
        const int koff = kb * BK;
        #pragma unroll
        for (int i = 0; i < 4; ++i) {
            if constexpr (XBF16) {
                RA0[i] = *(const bf16x8*)(pA016[i] + koff);
            } else {
                const float* a = pA0[i] + koff;
                RAF0[2 * i]     = *(const f32x4*)a;
                RAF0[2 * i + 1] = *(const f32x4*)(a + 4);
            }
        }
        if (has2) {
            #pragma unroll
            for (int i = 0; i < 4; ++i) {
                if constexpr (XBF16) {
                    RA1[i] = *(const bf16x8*)(pA116[i] + koff);
                } else {
                    const float* a = pA1[i] + koff;
                    RAF1[2 * i]     = *(const f32x4*)a;
                    RAF1[2 * i + 1] = *(const f32x4*)(a + 4);
                }
            }
        }
        #pragma unroll
        for (int i = 0; i < 2; ++i) {
            const float* b = pB[i] + koff;
            RB[2 * i]     = *(const f32x4*)b;
            RB[2 * i + 1] = *(const f32x4*)(b + 4);
        }
    };
    auto cvt_write = [&]() {
        #pragma unroll
        for (int i = 0; i < 4; ++i) {
            if constexpr (XBF16) {
                *(bf16x8*)&lds[A0_OFF + offWA[i]] = RA0[i];
            } else {
                bf16x8 va;
                #pragma unroll
                for (int j = 0; j < 4; ++j) {
                    va[j]     = (bf16_t)RAF0[2 * i][j];
                    va[j + 4] = (bf16_t)RAF0[2 * i + 1][j];
                }
                *(bf16x8*)&lds[A0_OFF + offWA[i]] = va;
            }
        }
        if (has2) {
            #pragma unroll
            for (int i = 0; i < 4; ++i) {
                if constexpr (XBF16) {
                    *(bf16x8*)&lds[A1_OFF + offWA[i]] = RA1[i];
                } else {
                    bf16x8 va;
                    #pragma unroll
                    for (int j = 0; j < 4; ++j) {
                        va[j]     = (bf16_t)RAF1[2 * i][j];
                        va[j + 4] = (bf16_t)RAF1[2 * i + 1][j];
                    }
                    *(bf16x8*)&lds[A1_OFF + offWA[i]] = va;
                }
            }
        }
        #pragma unroll
        for (int i = 0; i < 2; ++i) {
            bf16x8 vb;
            #pragma unroll
            for (int j = 0; j < 4; ++j) {
                vb[j]     = (bf16_t)RB[2 * i][j];
                vb[j + 4] = (bf16_t)RB[2 * i + 1][j];
            }
            *(bf16x8*)&lds[B_OFF + offWB[i]] = vb;
        }
    };
    auto compute = [&]() {
        #pragma unroll
        for (int kk = 0; kk < 2; ++kk) {
            bf16x8 bfr[2];
            #pragma unroll
            for (int n = 0; n < 2; ++n) bfr[n] = *(const bf16x8*)&lds[B_OFF + offB[kk][n]];
            #pragma unroll
            for (int m = 0; m < 4; ++m) {
                bf16x8 af = *(const bf16x8*)&lds[A0_OFF + offA[kk][m]];
                #pragma unroll
                for (int n = 0; n < 2; ++n)
                    acc0[m][n] = __builtin_amdgcn_mfma_f32_16x16x32_bf16(af, bfr[n], acc0[m][n], 0, 0, 0);
            }
            if (has2) {
                #pragma unroll
                for (int m = 0; m < 4; ++m) {
                    bf16x8 af = *(const bf16x8*)&lds[A1_OFF + offA[kk][m]];
                    #pragma unroll
                    for (int n = 0; n < 2; ++n)
                        acc1[m][n] = __builtin_amdgcn_mfma_f32_16x16x32_bf16(af, bfr[n], acc1[m][n], 0, 0, 0);
                }
            }
        }
    };

    // ---- pipelined main loop: 2 barriers per K-step ----
    issue(0);
    cvt_write();
    for (int kb = 0; kb < NK - 1; ++kb) {
        __syncthreads();
        issue(kb + 1);
        compute();
        __syncthreads();
        cvt_write();
    }
    __syncthreads();
    compute();

    // ---- epilogue (nt stores: out never re-read; keep L2 for x/w) ----
    auto store_pos = [&](int sp, f32x4 (&ac)[4][2]) {
        float* Og = out + (size_t)sp * DOUT + (size_t)(nb * BN);
        #pragma unroll
        for (int m = 0; m < 4; ++m) {
            const int rb = wr + m * 16 + (lane >> 4) * 4;
            #pragma unroll
            for (int r = 0; r < 4; ++r) {
                float* orow = Og + (size_t)(rb + r) * (S_DIM * DOUT);
                #pragma unroll
                for (int n = 0; n < 2; ++n)
                    __builtin_nontemporal_store(ac[m][n][r], &orow[wc + n * 16 + (lane & 15)]);
            }
        }
    };
    store_pos(s0, acc0);
    if (has2) store_pos(s1, acc1);
}

extern "C" void kernel_launch(void* const* d_in, const int* in_sizes, int n_in,
                              void* d_out, int out_size, void* d_ws, size_t ws_size,
                              hipStream_t stream) {
    const float* x         = (const float*)d_in[0];
    const float* w         = (const float*)d_in[1];
    const int*   layer_idx = (const int*)d_in[2];
    float*       out       = (float*)d_out;

    int*    tilemap = (int*)d_ws;                      // 2048 ints = 8 KB
    bf16_t* x16     = (bf16_t*)((char*)d_ws + 16384);  // 32 MB
    const size_t need = 16384 + (size_t)B_DIM * S_DIM * DIN * sizeof(bf16_t);

    rank_sort<<<1, S_DIM, 0, stream>>>(layer_idx, tilemap);

    if (ws_size >= need) {
        convert_x<<<(B_DIM * S_DIM * DIN / 8) / 256, 256, 0, stream>>>(x, x16);
        flex_linear_gemm<true><<<NTILES, dim3(256), 0, stream>>>(x, x16, w, layer_idx, tilemap, out);
    } else {
        flex_linear_gemm<false><<<NTILES, dim3(256), 0, stream>>>(x, x16, w, layer_idx, tilemap, out);
    }
}